// Round 1
// baseline (130.170 us; speedup 1.0000x reference)
//
#include <hip/hip_runtime.h>
#include <cstdint>
#include <cstddef>

// Problem dims
#define B_ROWS 65536
#define D_IN   784
#define KP     800      // D_IN padded to multiple of 32
#define D_H    300
#define NP     320      // D_H padded to multiple of 64
#define D_OUT  10
#define NP2    16       // D_OUT padded to 16
#define EPS    1e-5f
#define NBLK   1024     // blocks in gemm1 and gemm2 grids

typedef _Float16 half8  __attribute__((ext_vector_type(8)));
typedef float    floatx4 __attribute__((ext_vector_type(4)));

// Workspace layout (bytes). part[] aliases oc[]: part is consumed by k_reduce
// BEFORE k_gemm2 writes oc (strictly ordered on one stream).
#define OFF_S1   ((size_t)0)                       // _Float16[320*800]   = 512000
#define OFF_H    ((size_t)512000)                  // _Float16[65536*320] = 41943040
#define OFF_ST1  (OFF_H + (size_t)41943040)        // float[640]
#define OFF_W2   (OFF_ST1 + (size_t)2560)          // _Float16[16*320]    = 10240
#define OFF_ST2  (OFF_W2 + (size_t)10240)          // float[32]
#define OFF_OC   (OFF_ST2 + (size_t)256)           // float[65536*16]     = 4194304
#define OFF_P1   OFF_OC                            // float[640][1024] (alias, time-disjoint)
#define OFF_P2   (OFF_OC + (size_t)4194304)        // float[32][1024]     = 131072

// ---------------- K0: binarize W1 -> fp16 (+-1), zero-padded to [320][800]
__global__ void k_prep1(const float* __restrict__ W1, _Float16* __restrict__ S1)
{
    int idx = blockIdx.x * 256 + threadIdx.x;      // 0..255999
    int n = idx / KP;
    int k = idx - n * KP;
    float v = 0.0f;
    if (n < D_H && k < D_IN)
        v = (W1[n * D_IN + k] >= 0.0f) ? 1.0f : -1.0f;
    S1[idx] = (_Float16)v;
}

// ---------------- K1: h = x @ S1^T  (M=65536, N=320, K=800), fp16 MFMA
// BARRIER-FREE variant: no LDS, no __syncthreads in the K-loop. Each wave
// loads its A-fragments directly from global x (fp32 -> RTNE cvt to fp16 in
// registers), ping-ponged one 32-wide K-step ahead. The 4 quads of a wave
// cover one full 128B cache line per row; the 4x cross-wave redundancy on A
// rows is served by L1 (8 KB hot set/step). B (512 KB, L2-resident) is
// prefetched into ping-pong register sets as before. With no barriers the
// compiler maintains exact counted vmcnt waits and waves drift/overlap freely
// (the old structure paid a full vmcnt(0) drain at each of 50 __syncthreads).
// Fused per-block column sum/sumsq partials of h unchanged.

#define PF_B(BV, NK)                                                        \
    _Pragma("unroll")                                                       \
    for (int nt = 0; nt < 5; ++nt)                                          \
        BV[nt] = *(const half8*)(bb + (size_t)nt * 16 * KP + (NK));

#define ALOAD(AV, OFF)                                                      \
    _Pragma("unroll")                                                       \
    for (int mt = 0; mt < 4; ++mt) {                                        \
        AV[2 * mt]     = *(const floatx4*)(axp[mt] + (OFF));                \
        AV[2 * mt + 1] = *(const floatx4*)(axp[mt] + (OFF) + 4);            \
    }

#define ACVT(AV)                                                            \
    _Pragma("unroll")                                                       \
    for (int mt = 0; mt < 4; ++mt) {                                        \
        half8 hv;                                                           \
        _Pragma("unroll")                                                   \
        for (int i2 = 0; i2 < 4; ++i2) {                                    \
            hv[i2]     = (_Float16)AV[2 * mt][i2];                          \
            hv[4 + i2] = (_Float16)AV[2 * mt + 1][i2];                      \
        }                                                                   \
        a[mt] = hv;                                                         \
    }

#define COMPUTE(BV)                                                         \
    _Pragma("unroll")                                                       \
    for (int nt = 0; nt < 5; ++nt)                                          \
        _Pragma("unroll")                                                   \
        for (int mt = 0; mt < 4; ++mt)                                      \
            acc[mt][nt] = __builtin_amdgcn_mfma_f32_16x16x32_f16(           \
                a[mt], BV[nt], acc[mt][nt], 0, 0, 0);

__global__ __launch_bounds__(256) void k_gemm1(const float* __restrict__ x,
                                               const _Float16* __restrict__ S1,
                                               _Float16* __restrict__ h,
                                               float* __restrict__ part)
{
    const int t     = threadIdx.x;
    const int wave  = t >> 6;
    const int lane  = t & 63;
    const int row15 = lane & 15;
    const int quad  = lane >> 4;
    const int m0    = blockIdx.x * 64;

    // A fragment base pointers: lane (row15, quad) reads 8 consecutive fp32
    // at x[m0 + mt*16 + row15][kk + quad*8]. Quads 0..3 of a wave cover one
    // full 128B line per row.
    const float* axp[4];
#pragma unroll
    for (int mt = 0; mt < 4; ++mt)
        axp[mt] = x + (size_t)(m0 + mt * 16 + row15) * D_IN + quad * 8;
    // Tail step (kk=768): cols 768+quad*8 .. +8 overrun D_IN=784 for quad>=2.
    // Clamp those lanes' addresses back in-bounds (row base); their values
    // multiply S1's zero-padding (k>=784) so any finite data is correct.
    const int tailoff = (quad < 2) ? 768 : -(quad * 8);

    // B fragment base (MFMA B layout: lane holds col=row15, k=quad*8..+8)
    const _Float16* bb = S1 + (size_t)(wave * 80 + row15) * KP + quad * 8;

    floatx4 acc[4][5] = {};
    floatx4 av0[8], av1[8];
    half8   b0[5], b1[5];
    half8   a[4];

    ALOAD(av0, 0)
    PF_B(b0, 0)

    for (int i = 0; i < 12; ++i) {
        const int kk = i * 64;
        // even step 2i: computes av0/b0; prefetches step 2i+1
        ALOAD(av1, kk + 32)
        PF_B(b1, kk + 32)
        ACVT(av0)
        COMPUTE(b0)
        // odd step 2i+1: computes av1/b1; prefetches step 2i+2
        const int off2 = (i == 11) ? tailoff : (kk + 64);
        ALOAD(av0, off2)
        PF_B(b0, kk + 64)               // i=11 -> 768 (B zero-padded past 784)
        ACVT(av1)
        COMPUTE(b1)
    }
    // tail step 24: computes av0/b0 (k = 768..799, pad lanes hit B zeros)
    ACVT(av0)
    COMPUTE(b0)

    // --- epilogue: store h (C/D layout: col=lane&15, row=quad*4+r) + stats
    float s[5] = {}, q[5] = {};
#pragma unroll
    for (int mt = 0; mt < 4; ++mt)
#pragma unroll
        for (int nt = 0; nt < 5; ++nt)
#pragma unroll
            for (int r = 0; r < 4; ++r) {
                float v = acc[mt][nt][r];
                int m = m0 + mt * 16 + quad * 4 + r;
                int n = wave * 80 + nt * 16 + row15;
                h[(size_t)m * NP + n] = (_Float16)v;
                s[nt] += v;
                q[nt] += v * v;
            }
    // reduce over quad (waves own disjoint col ranges -> no cross-wave combine)
#pragma unroll
    for (int nt = 0; nt < 5; ++nt) {
        s[nt] += __shfl_xor(s[nt], 16); s[nt] += __shfl_xor(s[nt], 32);
        q[nt] += __shfl_xor(q[nt], 16); q[nt] += __shfl_xor(q[nt], 32);
    }
    if (quad == 0) {
#pragma unroll
        for (int nt = 0; nt < 5; ++nt) {
            int col = wave * 80 + nt * 16 + row15;
            part[(size_t)col * NBLK + blockIdx.x]        = s[nt];
            part[(size_t)(NP + col) * NBLK + blockIdx.x] = q[nt];
        }
    }
}

// ---------------- K2: contention-free reduce of per-block partials
// (one block per output element; partial stride fixed at NBLK=1024)
__global__ void k_reduce(const float* __restrict__ part, float* __restrict__ st)
{
    __shared__ float red[4];
    const int c = blockIdx.x;
    const int t = threadIdx.x;           // 256
    const float* p = part + (size_t)c * NBLK;
    float s = p[t] + p[t + 256] + p[t + 512] + p[t + 768];
#pragma unroll
    for (int off = 1; off < 64; off <<= 1) s += __shfl_xor(s, off);
    if ((t & 63) == 0) red[t >> 6] = s;
    __syncthreads();
    if (t == 0) st[c] = red[0] + red[1] + red[2] + red[3];
}

// ---------------- K3: fold BN1 scale into binarized W2 -> w2h[16][320] fp16
__global__ void k_prep2(const float* __restrict__ st, const float* __restrict__ gamma1,
                        const float* __restrict__ W2, _Float16* __restrict__ w2h)
{
    int j = threadIdx.x;                 // 0..319
    float mean = st[j] * (1.0f / 65536.0f);
    float var  = st[NP + j] * (1.0f / 65536.0f) - mean * mean;
    float a1   = 0.0f;
    if (j < D_H) a1 = gamma1[j] / sqrtf(var + EPS);
    for (int k = 0; k < NP2; ++k) {
        float w = 0.0f;
        if (k < D_OUT && j < D_H)
            w = (W2[k * D_H + j] >= 0.0f) ? a1 : -a1;
        w2h[k * NP + j] = (_Float16)w;
    }
}

// ---------------- K4: oc = h @ w2h^T  (K=320, N=16) + per-block stat partials
__global__ __launch_bounds__(256) void k_gemm2(const _Float16* __restrict__ h,
                                               const _Float16* __restrict__ w2h,
                                               float* __restrict__ oc,
                                               float* __restrict__ part2)
{
    __shared__ _Float16 Wlds[16][328];   // pad 320->328 to break bank conflicts
    __shared__ float reds[4][16], redq[4][16];
    const int t     = threadIdx.x;
    const int wave  = t >> 6;
    const int lane  = t & 63;
    const int row15 = lane & 15;
    const int quad  = lane >> 4;

    for (int c = t; c < 640; c += 256) { // 16*320/8 chunks
        int r  = c / 40;
        int cc = (c - r * 40) * 8;
        *(half8*)&Wlds[r][cc] = *(const half8*)(w2h + r * NP + cc);
    }
    __syncthreads();

    const int m0 = blockIdx.x * 64 + wave * 16;
    const _Float16* hp = h + (size_t)(m0 + row15) * NP + quad * 8;
    floatx4 acc = {};
#pragma unroll
    for (int kk = 0; kk < NP; kk += 32) {
        half8 a2 = *(const half8*)(hp + kk);
        half8 b2 = *(const half8*)&Wlds[row15][kk + quad * 8];
        acc = __builtin_amdgcn_mfma_f32_16x16x32_f16(a2, b2, acc, 0, 0, 0);
    }
    float s = 0.f, q = 0.f;
#pragma unroll
    for (int r = 0; r < 4; ++r) {
        float v = acc[r];
        oc[(size_t)(m0 + quad * 4 + r) * NP2 + row15] = v;
        s += v; q += v * v;
    }
    s += __shfl_xor(s, 16); s += __shfl_xor(s, 32);
    q += __shfl_xor(q, 16); q += __shfl_xor(q, 32);
    if (lane < 16) { reds[wave][row15] = s; redq[wave][row15] = q; }
    __syncthreads();
    if (t < 16) {
        float S = reds[0][t] + reds[1][t] + reds[2][t] + reds[3][t];
        float Q = redq[0][t] + redq[1][t] + redq[2][t] + redq[3][t];
        part2[(size_t)t * NBLK + blockIdx.x]          = S;
        part2[(size_t)(16 + t) * NBLK + blockIdx.x]   = Q;
    }
}

// ---------------- K5: BN2 epilogue -> out[65536][10] fp32
__global__ void k_final(const float* __restrict__ oc, const float* __restrict__ st2,
                        const float* __restrict__ gamma2, const float* __restrict__ beta2,
                        float* __restrict__ out)
{
    int idx = blockIdx.x * 256 + threadIdx.x;    // 2560*256 == 655360 exactly
    int m = idx / 10;
    int k = idx - m * 10;
    float mean = st2[k] * (1.0f / 65536.0f);
    float var  = st2[16 + k] * (1.0f / 65536.0f) - mean * mean;
    float sc   = gamma2[k] / sqrtf(var + EPS);
    out[idx] = (oc[(size_t)m * NP2 + k] - mean) * sc + beta2[k];
}

extern "C" void kernel_launch(void* const* d_in, const int* in_sizes, int n_in,
                              void* d_out, int out_size, void* d_ws, size_t ws_size,
                              hipStream_t stream)
{
    const float* x      = (const float*)d_in[0];
    const float* W1     = (const float*)d_in[1];
    const float* gamma1 = (const float*)d_in[2];
    // d_in[3] = beta1 : algebraically cancels under BN2's mean subtraction
    const float* W2     = (const float*)d_in[4];
    const float* gamma2 = (const float*)d_in[5];
    const float* beta2  = (const float*)d_in[6];
    float* out = (float*)d_out;

    char* ws = (char*)d_ws;
    _Float16* S1    = (_Float16*)(ws + OFF_S1);
    _Float16* h     = (_Float16*)(ws + OFF_H);
    float*    st1   = (float*)(ws + OFF_ST1);
    _Float16* w2h   = (_Float16*)(ws + OFF_W2);
    float*    st2   = (float*)(ws + OFF_ST2);
    float*    oc    = (float*)(ws + OFF_OC);
    float*    part  = (float*)(ws + OFF_P1);   // aliases oc (time-disjoint)
    float*    part2 = (float*)(ws + OFF_P2);

    k_prep1 <<<1000, 256, 0, stream>>>(W1, S1);
    k_gemm1 <<<NBLK, 256, 0, stream>>>(x, S1, h, part);
    k_reduce<<<640, 256, 0, stream>>>(part, st1);
    k_prep2 <<<1, 320, 0, stream>>>(st1, gamma1, W2, w2h);
    k_gemm2 <<<NBLK, 256, 0, stream>>>(h, w2h, oc, part2);
    k_reduce<<<32, 256, 0, stream>>>(part2, st2);
    k_final <<<2560, 256, 0, stream>>>(oc, st2, gamma2, beta2, out);
}

// Round 2
// 111.160 us; speedup vs baseline: 1.1710x; 1.1710x over previous
//
#include <hip/hip_runtime.h>
#include <cstdint>
#include <cstddef>

// Problem dims
#define B_ROWS 65536
#define D_IN   784
#define KP     800      // D_IN padded to multiple of 32
#define D_H    300
#define NP     320      // D_H padded to multiple of 64
#define D_OUT  10
#define NP2    16       // D_OUT padded to 16
#define EPS    1e-5f
#define NBLK   1024     // blocks in gemm1 and gemm2 grids
#define APAD   44       // LDS A row stride in halfs (44*2=88 B -> <=2-way banks)

typedef _Float16 half8  __attribute__((ext_vector_type(8)));
typedef float    floatx4 __attribute__((ext_vector_type(4)));

// Workspace layout (bytes). part[] aliases oc[]: part is consumed by k_reduce
// BEFORE k_gemm2 writes oc (strictly ordered on one stream).
#define OFF_S1   ((size_t)0)                       // _Float16[320*800]   = 512000
#define OFF_H    ((size_t)512000)                  // _Float16[65536*320] = 41943040
#define OFF_ST1  (OFF_H + (size_t)41943040)        // float[640]
#define OFF_W2   (OFF_ST1 + (size_t)2560)          // _Float16[16*320]    = 10240
#define OFF_ST2  (OFF_W2 + (size_t)10240)          // float[32]
#define OFF_OC   (OFF_ST2 + (size_t)256)           // float[65536*16]     = 4194304
#define OFF_P1   OFF_OC                            // float[640][1024] (alias, time-disjoint)
#define OFF_P2   (OFF_OC + (size_t)4194304)        // float[32][1024]     = 131072

// ---------------- K0: binarize W1 -> fp16 (+-1), zero-padded to [320][800]
__global__ void k_prep1(const float* __restrict__ W1, _Float16* __restrict__ S1)
{
    int idx = blockIdx.x * 256 + threadIdx.x;      // 0..255999
    int n = idx / KP;
    int k = idx - n * KP;
    float v = 0.0f;
    if (n < D_H && k < D_IN)
        v = (W1[n * D_IN + k] >= 0.0f) ? 1.0f : -1.0f;
    S1[idx] = (_Float16)v;
}

// ---------------- K1: h = x @ S1^T  (M=65536, N=320, K=800), fp16 MFMA
// Round-0 dataflow (A staged once/block: fp32 load -> cvt -> fp16 ds_write,
// padded rows; B register ping-pong from L2) with the sync structure fixed:
//  - raw s_barrier + lgkmcnt(0) only (NO vmcnt drain -> B prefetch and the
//    deep x prefetch survive the barrier; __syncthreads forced vmcnt(0))
//  - x prefetch depth 2 (two register sets): x(s+2) issued at step s,
//    consumed by STAGE_STORE at step s+1 -> ~1.7 steps of HBM-latency cover
//    (was ~0.5 step -> per-step vmcnt stall was the dominant idle).
// Double-buffer invariant identical to round 0 (read buf[s%2], write
// buf[(s+1)%2], one barrier per step), so no new race structure.
// sched_barrier(0) fences pin all memory ops on their side of the barrier.

#define PF_B(BV, NK)                                                        \
    _Pragma("unroll")                                                       \
    for (int nt = 0; nt < 5; ++nt)                                          \
        BV[nt] = *(const half8*)(bb + (size_t)nt * 16 * KP + (NK));

#define STAGE_LOAD(V0, V1, KK)                                              \
    {                                                                       \
        V0 = (floatx4){}; V1 = (floatx4){};                                 \
        if ((KK) + sc < D_IN) {            /* chunk-uniform: D_IN%8==0 */   \
            V0 = *(const floatx4*)(sxp + (KK));                             \
            V1 = *(const floatx4*)(sxp + (KK) + 4);                         \
        }                                                                   \
    }

#define STAGE_STORE(V0, V1, BUF)                                            \
    {                                                                       \
        half8 hv;                                                           \
        _Pragma("unroll")                                                   \
        for (int i2 = 0; i2 < 4; ++i2) {                                    \
            hv[i2]     = (_Float16)V0[i2];                                  \
            hv[4 + i2] = (_Float16)V1[i2];                                  \
        }                                                                   \
        *(half8*)&Alds[BUF][srow][sc] = hv;                                 \
    }

#define AFRAG(BUF)                                                          \
    _Pragma("unroll")                                                       \
    for (int mt = 0; mt < 4; ++mt)                                          \
        a[mt] = *(const half8*)&Alds[BUF][mt * 16 + row15][quad * 8];

#define COMPUTE(BV)                                                         \
    _Pragma("unroll")                                                       \
    for (int nt = 0; nt < 5; ++nt)                                          \
        _Pragma("unroll")                                                   \
        for (int mt = 0; mt < 4; ++mt)                                      \
            acc[mt][nt] = __builtin_amdgcn_mfma_f32_16x16x32_f16(           \
                a[mt], BV[nt], acc[mt][nt], 0, 0, 0);

// Publish LDS writes to the workgroup WITHOUT draining vmcnt: ds ops done
// (lgkmcnt(0)), sched fences so nothing migrates across, raw barrier.
#define BAR()                                                               \
    asm volatile("s_waitcnt lgkmcnt(0)" ::: "memory");                      \
    __builtin_amdgcn_sched_barrier(0);                                      \
    __builtin_amdgcn_s_barrier();                                           \
    __builtin_amdgcn_sched_barrier(0);

__global__ __launch_bounds__(256) void k_gemm1(const float* __restrict__ x,
                                               const _Float16* __restrict__ S1,
                                               _Float16* __restrict__ h,
                                               float* __restrict__ part)
{
    __shared__ _Float16 Alds[2][64][APAD];   // 2 x 5.5 KB
    const int t     = threadIdx.x;
    const int wave  = t >> 6;
    const int lane  = t & 63;
    const int row15 = lane & 15;
    const int quad  = lane >> 4;
    const int m0    = blockIdx.x * 64;

    // staging assignment: thread t -> row t>>2, half-chunk (t&3)*8
    const int srow = t >> 2;
    const int sc   = (t & 3) * 8;
    const float* sxp = x + (size_t)(m0 + srow) * D_IN + sc;

    // B fragment base (MFMA B layout: lane holds col=row15, k=quad*8..+8)
    const _Float16* bb = S1 + (size_t)(wave * 80 + row15) * KP + quad * 8;

    floatx4 acc[4][5] = {};
    half8   b0[5], b1[5];
    half8   a[4];
    floatx4 a0, a1, c0, c1;      // two x-prefetch register sets (depth 2)

    // prologue: buf0 <- x(0); svB(c) <- x(1); b0 <- B(0)
    STAGE_LOAD(a0, a1, 0)
    PF_B(b0, 0)
    STAGE_LOAD(c0, c1, 32)
    STAGE_STORE(a0, a1, 0)       // waits only the x(0) loads (counted vmcnt)
    BAR()

    for (int i = 0; i < 12; ++i) {
        const int kk = i * 64;
        // even step s=2i: reads buf0/b0; svB holds x(s+1); issue x(s+2)->svA
        STAGE_LOAD(a0, a1, kk + 64)
        PF_B(b1, kk + 32)
        AFRAG(0)
        COMPUTE(b0)
        STAGE_STORE(c0, c1, 1)   // buf1 <- x(s+1), issued one full step ago
        BAR()
        // odd step s=2i+1: reads buf1/b1; svA holds x(s+1); issue x(s+2)->svB
        STAGE_LOAD(c0, c1, kk + 96)   // i=11 -> koff 800: guard zeroes (no load)
        PF_B(b0, kk + 64)             // i=11 -> B(24) at koff 768
        AFRAG(1)
        COMPUTE(b1)
        STAGE_STORE(a0, a1, 0)   // buf0 <- x(s+1)
        BAR()
    }
    // tail step 24: reads buf0/b0 (k = 768..799, pad lanes hit B zeros)
    AFRAG(0)
    COMPUTE(b0)

    // --- epilogue: store h (C/D layout: col=lane&15, row=quad*4+r) + stats
    float s[5] = {}, q[5] = {};
#pragma unroll
    for (int mt = 0; mt < 4; ++mt)
#pragma unroll
        for (int nt = 0; nt < 5; ++nt)
#pragma unroll
            for (int r = 0; r < 4; ++r) {
                float v = acc[mt][nt][r];
                int m = m0 + mt * 16 + quad * 4 + r;
                int n = wave * 80 + nt * 16 + row15;
                h[(size_t)m * NP + n] = (_Float16)v;
                s[nt] += v;
                q[nt] += v * v;
            }
    // reduce over quad (waves own disjoint col ranges -> no cross-wave combine)
#pragma unroll
    for (int nt = 0; nt < 5; ++nt) {
        s[nt] += __shfl_xor(s[nt], 16); s[nt] += __shfl_xor(s[nt], 32);
        q[nt] += __shfl_xor(q[nt], 16); q[nt] += __shfl_xor(q[nt], 32);
    }
    if (quad == 0) {
#pragma unroll
        for (int nt = 0; nt < 5; ++nt) {
            int col = wave * 80 + nt * 16 + row15;
            part[(size_t)col * NBLK + blockIdx.x]        = s[nt];
            part[(size_t)(NP + col) * NBLK + blockIdx.x] = q[nt];
        }
    }
}

// ---------------- K2: contention-free reduce of per-block partials
// (one block per output element; partial stride fixed at NBLK=1024)
__global__ void k_reduce(const float* __restrict__ part, float* __restrict__ st)
{
    __shared__ float red[4];
    const int c = blockIdx.x;
    const int t = threadIdx.x;           // 256
    const float* p = part + (size_t)c * NBLK;
    float s = p[t] + p[t + 256] + p[t + 512] + p[t + 768];
#pragma unroll
    for (int off = 1; off < 64; off <<= 1) s += __shfl_xor(s, off);
    if ((t & 63) == 0) red[t >> 6] = s;
    __syncthreads();
    if (t == 0) st[c] = red[0] + red[1] + red[2] + red[3];
}

// ---------------- K3: fold BN1 scale into binarized W2 -> w2h[16][320] fp16
__global__ void k_prep2(const float* __restrict__ st, const float* __restrict__ gamma1,
                        const float* __restrict__ W2, _Float16* __restrict__ w2h)
{
    int j = threadIdx.x;                 // 0..319
    float mean = st[j] * (1.0f / 65536.0f);
    float var  = st[NP + j] * (1.0f / 65536.0f) - mean * mean;
    float a1   = 0.0f;
    if (j < D_H) a1 = gamma1[j] / sqrtf(var + EPS);
    for (int k = 0; k < NP2; ++k) {
        float w = 0.0f;
        if (k < D_OUT && j < D_H)
            w = (W2[k * D_H + j] >= 0.0f) ? a1 : -a1;
        w2h[k * NP + j] = (_Float16)w;
    }
}

// ---------------- K4: oc = h @ w2h^T  (K=320, N=16) + per-block stat partials
__global__ __launch_bounds__(256) void k_gemm2(const _Float16* __restrict__ h,
                                               const _Float16* __restrict__ w2h,
                                               float* __restrict__ oc,
                                               float* __restrict__ part2)
{
    __shared__ _Float16 Wlds[16][328];   // pad 320->328 to break bank conflicts
    __shared__ float reds[4][16], redq[4][16];
    const int t     = threadIdx.x;
    const int wave  = t >> 6;
    const int lane  = t & 63;
    const int row15 = lane & 15;
    const int quad  = lane >> 4;

    for (int c = t; c < 640; c += 256) { // 16*320/8 chunks
        int r  = c / 40;
        int cc = (c - r * 40) * 8;
        *(half8*)&Wlds[r][cc] = *(const half8*)(w2h + r * NP + cc);
    }
    __syncthreads();

    const int m0 = blockIdx.x * 64 + wave * 16;
    const _Float16* hp = h + (size_t)(m0 + row15) * NP + quad * 8;
    floatx4 acc = {};
#pragma unroll
    for (int kk = 0; kk < NP; kk += 32) {
        half8 a2 = *(const half8*)(hp + kk);
        half8 b2 = *(const half8*)&Wlds[row15][kk + quad * 8];
        acc = __builtin_amdgcn_mfma_f32_16x16x32_f16(a2, b2, acc, 0, 0, 0);
    }
    float s = 0.f, q = 0.f;
#pragma unroll
    for (int r = 0; r < 4; ++r) {
        float v = acc[r];
        oc[(size_t)(m0 + quad * 4 + r) * NP2 + row15] = v;
        s += v; q += v * v;
    }
    s += __shfl_xor(s, 16); s += __shfl_xor(s, 32);
    q += __shfl_xor(q, 16); q += __shfl_xor(q, 32);
    if (lane < 16) { reds[wave][row15] = s; redq[wave][row15] = q; }
    __syncthreads();
    if (t < 16) {
        float S = reds[0][t] + reds[1][t] + reds[2][t] + reds[3][t];
        float Q = redq[0][t] + redq[1][t] + redq[2][t] + redq[3][t];
        part2[(size_t)t * NBLK + blockIdx.x]          = S;
        part2[(size_t)(16 + t) * NBLK + blockIdx.x]   = Q;
    }
}

// ---------------- K5: BN2 epilogue -> out[65536][10] fp32
__global__ void k_final(const float* __restrict__ oc, const float* __restrict__ st2,
                        const float* __restrict__ gamma2, const float* __restrict__ beta2,
                        float* __restrict__ out)
{
    int idx = blockIdx.x * 256 + threadIdx.x;    // 2560*256 == 655360 exactly
    int m = idx / 10;
    int k = idx - m * 10;
    float mean = st2[k] * (1.0f / 65536.0f);
    float var  = st2[16 + k] * (1.0f / 65536.0f) - mean * mean;
    float sc   = gamma2[k] / sqrtf(var + EPS);
    out[idx] = (oc[(size_t)m * NP2 + k] - mean) * sc + beta2[k];
}

extern "C" void kernel_launch(void* const* d_in, const int* in_sizes, int n_in,
                              void* d_out, int out_size, void* d_ws, size_t ws_size,
                              hipStream_t stream)
{
    const float* x      = (const float*)d_in[0];
    const float* W1     = (const float*)d_in[1];
    const float* gamma1 = (const float*)d_in[2];
    // d_in[3] = beta1 : algebraically cancels under BN2's mean subtraction
    const float* W2     = (const float*)d_in[4];
    const float* gamma2 = (const float*)d_in[5];
    const float* beta2  = (const float*)d_in[6];
    float* out = (float*)d_out;

    char* ws = (char*)d_ws;
    _Float16* S1    = (_Float16*)(ws + OFF_S1);
    _Float16* h     = (_Float16*)(ws + OFF_H);
    float*    st1   = (float*)(ws + OFF_ST1);
    _Float16* w2h   = (_Float16*)(ws + OFF_W2);
    float*    st2   = (float*)(ws + OFF_ST2);
    float*    oc    = (float*)(ws + OFF_OC);
    float*    part  = (float*)(ws + OFF_P1);   // aliases oc (time-disjoint)
    float*    part2 = (float*)(ws + OFF_P2);

    k_prep1 <<<1000, 256, 0, stream>>>(W1, S1);
    k_gemm1 <<<NBLK, 256, 0, stream>>>(x, S1, h, part);
    k_reduce<<<640, 256, 0, stream>>>(part, st1);
    k_prep2 <<<1, 320, 0, stream>>>(st1, gamma1, W2, w2h);
    k_gemm2 <<<NBLK, 256, 0, stream>>>(h, w2h, oc, part2);
    k_reduce<<<32, 256, 0, stream>>>(part2, st2);
    k_final <<<2560, 256, 0, stream>>>(oc, st2, gamma2, beta2, out);
}